// Round 7
// baseline (2681.748 us; speedup 1.0000x reference)
//
#include <hip/hip_runtime.h>

// RNN: out[n,t,:] = tanh(x[n,t,:]@Wx + b + h_{t-1}@Wh),  h_{-1} = h0
// N=64, T=512, D=512, H=1024, fp32 in/out.
// Round 7: Wh pinned in AGPRs (one-shot "+a" touch: non-rematerializable,
// MFMA reads AGPR operands directly). Wave = 64 cols x K=256 (64 frags);
// 64 blocks (4 groups x 16 col-tiles); per-wave flags; halved h IC traffic.

#define NN 64
#define TT 512
#define DD 512
#define HH 1024

typedef unsigned int  u32;
typedef unsigned short u16;

typedef __attribute__((ext_vector_type(8))) short bf16x8;
typedef __attribute__((ext_vector_type(4))) float f32x4;
typedef __attribute__((ext_vector_type(4))) u32   u32x4;
typedef __attribute__((ext_vector_type(2))) u32   u32x2;

#define MFMA16(a, b, c) __builtin_amdgcn_mfma_f32_16x16x32_bf16((a), (b), (c), 0, 0, 0)

__device__ __forceinline__ u32 bf16r(float f) {          // RTNE fp32->bf16 (bits)
    u32 u = __float_as_uint(f);
    return (u + 0x7fffu + ((u >> 16) & 1u)) >> 16;
}
__device__ __forceinline__ float bf16tof(u32 h) { return __uint_as_float(h << 16); }
__device__ __forceinline__ void split2(float f, u32& hi, u32& lo) {
    hi = bf16r(f);
    lo = bf16r(f - bf16tof(hi));
}

// ---- system-scope (sc0 sc1) ops; no "memory" clobbers (volatile asm mutual
// order carries the protocol; clobbers would forbid register caching).
__device__ __forceinline__ u32x4 ld16_sys(const u16* p) {   // issue-only
    u32x4 v;
    asm volatile("global_load_dwordx4 %0, %1, off sc0 sc1" : "=v"(v) : "v"(p));
    return v;
}
__device__ __forceinline__ void st8_sys(u32* p, u32 v0, u32 v1) {
    u32x2 v = {v0, v1};
    asm volatile("global_store_dwordx2 %0, %1, off sc0 sc1" :: "v"(p), "v"(v));
}
__device__ __forceinline__ u32 ld_flag(const u32* p) {
    u32 v;
    asm volatile("global_load_dword %0, %1, off sc0 sc1\n\ts_waitcnt vmcnt(0)"
                 : "=v"(v) : "v"(p));
    return v;
}
__device__ __forceinline__ void st_flag(u32* p, u32 v) {
    asm volatile("global_store_dword %0, %1, off sc0 sc1" :: "v"(p), "v"(v));
}
__device__ __forceinline__ void wait_vm0() {
    asm volatile("s_waitcnt vmcnt(0)");
}

__device__ __forceinline__ float fast_tanh(float x) {
    float e = __expf(2.0f * x);
    return 1.0f - __fdividef(2.0f, e + 1.0f);   // exact +/-1 saturation
}

// one-shot AGPR pin: defines values in AGPRs via volatile asm => the
// allocator cannot rematerialize them from memory afterwards.
#define PIN8(a0,a1,a2,a3,a4,a5,a6,a7) \
    asm volatile("" : "+a"(a0), "+a"(a1), "+a"(a2), "+a"(a3), \
                      "+a"(a4), "+a"(a5), "+a"(a6), "+a"(a7))

// ---------------------------------------------------------------------------
// Prep: pack Wx and Wh into MFMA-fragment order (hi/lo bf16); split h0.
// Fragment layout for 16x16x32: p = ((jt*KB + kb)*64 + lane)*8 + e
//   j = jt*16 + (lane&15),  k = kb*32 + (lane>>4)*8 + e
// ---------------------------------------------------------------------------
__global__ __launch_bounds__(256) void prep_kernel(
    const float* __restrict__ Wx, const float* __restrict__ Wh,
    const float* __restrict__ h0,
    u16* __restrict__ WxPh, u16* __restrict__ WxPl,
    u16* __restrict__ WhPh, u16* __restrict__ WhPl,
    u16* __restrict__ h0H,  u16* __restrict__ h0L)
{
    const int stride = gridDim.x * 256;
    const int gid = blockIdx.x * 256 + threadIdx.x;

    for (int p = gid; p < 64 * 16 * 64 * 8; p += stride) {   // Wx
        int e = p & 7, l = (p >> 3) & 63, kb = (p >> 9) & 15, jt = p >> 13;
        int j = jt * 16 + (l & 15);
        int k = kb * 32 + ((l >> 4) << 3) + e;
        u32 hi, lo; split2(Wx[k * HH + j], hi, lo);
        WxPh[p] = (u16)hi; WxPl[p] = (u16)lo;
    }
    for (int p = gid; p < 64 * 32 * 64 * 8; p += stride) {   // Wh
        int e = p & 7, l = (p >> 3) & 63, kb = (p >> 9) & 31, jt = p >> 14;
        int j = jt * 16 + (l & 15);
        int k = kb * 32 + ((l >> 4) << 3) + e;
        u32 hi, lo; split2(Wh[k * HH + j], hi, lo);
        WhPh[p] = (u16)hi; WhPl[p] = (u16)lo;
    }
    for (int p = gid; p < NN * HH; p += stride) {            // h0 -> parity 0
        u32 hi, lo; split2(h0[p], hi, lo);
        h0H[p] = (u16)hi; h0L[p] = (u16)lo;
    }
}

// ---------------------------------------------------------------------------
// Phase 1: out = x@Wx + b   (split-bf16, 128x128 tiles, grid 2048)
// ---------------------------------------------------------------------------
__global__ __launch_bounds__(256) void gemm_kernel(
    const float* __restrict__ x, const float* __restrict__ b,
    const u16* __restrict__ WxPh, const u16* __restrict__ WxPl,
    float* __restrict__ out)
{
    __shared__ __align__(16) u32 ldsA[2][128][20];

    const int tid = threadIdx.x;
    const int bid = blockIdx.x;
    const int w   = tid >> 6;
    const int l   = tid & 63;
    const int wm = w >> 1, wj = w & 1;

    const int m0 = (bid >> 3) * 128;
    const int jb = bid & 7;
    const int j0 = jb * 128;

    f32x4 acc[4][4] = {};
    for (int ks = 0; ks < 16; ++ks) {
        const int k0 = ks * 32;
        #pragma unroll
        for (int it = 0; it < 8; ++it) {
            int idx = it * 256 + tid;
            int m = idx >> 4, kp = idx & 15;
            float2 v = *(const float2*)(x + (m0 + m) * DD + k0 + kp * 2);
            u32 h0b, l0b, h1b, l1b;
            split2(v.x, h0b, l0b);
            split2(v.y, h1b, l1b);
            ldsA[0][m][kp] = h0b | (h1b << 16);
            ldsA[1][m][kp] = l0b | (l1b << 16);
        }
        __syncthreads();

        bf16x8 afh[4], afl[4], bfh[4], bfl[4];
        #pragma unroll
        for (int mt4 = 0; mt4 < 4; ++mt4) {
            int row = wm * 64 + mt4 * 16 + (l & 15);
            int co  = (l >> 4) * 4;
            afh[mt4] = *(const bf16x8*)&ldsA[0][row][co];
            afl[mt4] = *(const bf16x8*)&ldsA[1][row][co];
        }
        #pragma unroll
        for (int jt4 = 0; jt4 < 4; ++jt4) {
            int jtile = jb * 8 + wj * 4 + jt4;
            int off = ((jtile * 16 + ks) * 64 + l) * 8;
            bfh[jt4] = *(const bf16x8*)(WxPh + off);
            bfl[jt4] = *(const bf16x8*)(WxPl + off);
        }
        #pragma unroll
        for (int mt4 = 0; mt4 < 4; ++mt4)
            #pragma unroll
            for (int jt4 = 0; jt4 < 4; ++jt4) {
                acc[mt4][jt4] = MFMA16(afh[mt4], bfh[jt4], acc[mt4][jt4]);
                acc[mt4][jt4] = MFMA16(afh[mt4], bfl[jt4], acc[mt4][jt4]);
                acc[mt4][jt4] = MFMA16(afl[mt4], bfh[jt4], acc[mt4][jt4]);
            }
        __syncthreads();
    }
    #pragma unroll
    for (int jt4 = 0; jt4 < 4; ++jt4) {
        int j = j0 + wj * 64 + jt4 * 16 + (l & 15);
        float bj = b[j];
        #pragma unroll
        for (int mt4 = 0; mt4 < 4; ++mt4)
            #pragma unroll
            for (int r = 0; r < 4; ++r) {
                int m = m0 + wm * 64 + mt4 * 16 + (l >> 4) * 4 + r;
                out[m * HH + j] = acc[mt4][jt4][r] + bj;
            }
    }
}

// ---------------------------------------------------------------------------
// Phase 2: scan. Grid 64 x 256. Group g = bid&3 owns rows [16g,16g+16);
// block cb = bid>>2 owns cols [64cb,64cb+64); wave w owns k [256w,+256).
// Wh per wave: 4 j-tiles x 8 k-frags x {hi,lo} = 64 frags = 256 AGPRs.
// flags[g*64 + cb*4 + v] = t+1  <=>  block cb wave v posted rows 4v..4v+3
// of h_t. Consumer wave w polls 16 flags (blocks 4w..4w+3 x 4 waves) with
// 16 lanes; block barrier joins waves => full-group quiescence before any
// parity-buffer overwrite (lap-safe).
// ---------------------------------------------------------------------------
__global__ __launch_bounds__(256, 1) void scan_kernel(
    const u16* __restrict__ WhPh, const u16* __restrict__ WhPl,
    u16* __restrict__ hbH, u16* __restrict__ hbL,   // [2 parity][64][1024]
    float* __restrict__ out, u32* __restrict__ flags)
{
    __shared__ float ldsRed[2][4][16][68];

    const int tid = threadIdx.x;
    const int bid = blockIdx.x;
    const int g   = bid & 3;
    const int cb  = bid >> 2;        // col tile (64 cols)
    const int w   = tid >> 6;
    const int l   = tid & 63;

    // Wh fragments: jt = cb*4+jj, kb = w*8+i
    bf16x8 Bh[4][8], Bl[4][8];
    #pragma unroll
    for (int jj = 0; jj < 4; ++jj)
        #pragma unroll
        for (int i = 0; i < 8; ++i) {
            int off = (((cb * 4 + jj) * 32 + w * 8 + i) * 64 + l) * 8;
            Bh[jj][i] = *(const bf16x8*)(WhPh + off);
            Bl[jj][i] = *(const bf16x8*)(WhPl + off);
        }
    // one-shot AGPR pin (non-rematerializable after this)
    #pragma unroll
    for (int jj = 0; jj < 4; ++jj) {
        PIN8(Bh[jj][0], Bh[jj][1], Bh[jj][2], Bh[jj][3],
             Bh[jj][4], Bh[jj][5], Bh[jj][6], Bh[jj][7]);
        PIN8(Bl[jj][0], Bl[jj][1], Bl[jj][2], Bl[jj][3],
             Bl[jj][4], Bl[jj][5], Bl[jj][6], Bl[jj][7]);
    }

    const int nA    = g * 16 + (l & 15);       // A-frag batch row
    const int kbase = w * 256 + ((l >> 4) << 3);

    const int r  = tid >> 4;                   // output row 0..15 (wave v: 4v..4v+3)
    const int c0 = (tid & 15) * 4;             // 4-col slice
    const int nF = g * 16 + r;
    const int jE = cb * 64 + c0;

    u32* gflags = flags + g * 64;
    const u32* pollp = gflags + 16 * w + l;    // l<16: block 4w+(l>>2), wave l&3

    float4 xw = *(const float4*)&out[(nF * TT) * HH + jE];

    for (int t = 0; t < TT; ++t) {
        const int par = t & 1;

        if (t > 0) {                           // wait for h_{t-1} (my k-slice)
            const u32 tgt = (u32)t;
            while (true) {
                u32 fv = tgt;
                if (l < 16) fv = ld_flag(pollp);
                if (__ballot(fv >= tgt) == ~0ull) break;
            }
        }

        const u16* hH = hbH + par * NN * HH + nA * HH + kbase;
        const u16* hL = hbL + par * NN * HH + nA * HH + kbase;

        u32x4 ahraw[8], alraw[8];
        #pragma unroll
        for (int i = 0; i < 8; ++i) {
            ahraw[i] = ld16_sys(hH + i * 32);
            alraw[i] = ld16_sys(hL + i * 32);
        }
        wait_vm0();
        __builtin_amdgcn_sched_barrier(0);

        f32x4 ahh[4] = {}, ahl[4] = {}, alh[4] = {};
        #pragma unroll
        for (int i = 0; i < 8; ++i) {
            bf16x8 Ahv = __builtin_bit_cast(bf16x8, ahraw[i]);
            bf16x8 Alv = __builtin_bit_cast(bf16x8, alraw[i]);
            #pragma unroll
            for (int jj = 0; jj < 4; ++jj) {
                ahh[jj] = MFMA16(Ahv, Bh[jj][i], ahh[jj]);
                ahl[jj] = MFMA16(Ahv, Bl[jj][i], ahl[jj]);
                alh[jj] = MFMA16(Alv, Bh[jj][i], alh[jj]);
            }
        }

        // per-wave partials -> LDS[par]: C elem e <-> row (l>>4)*4+e, col jj*16+(l&15)
        #pragma unroll
        for (int jj = 0; jj < 4; ++jj) {
            f32x4 s4 = ahh[jj] + ahl[jj] + alh[jj];
            #pragma unroll
            for (int e = 0; e < 4; ++e)
                ldsRed[par][w][(l >> 4) * 4 + e][jj * 16 + (l & 15)] = s4[e];
        }
        __syncthreads();

        float4 s;
        {
            float4 s0 = *(const float4*)&ldsRed[par][0][r][c0];
            float4 s1 = *(const float4*)&ldsRed[par][1][r][c0];
            float4 s2 = *(const float4*)&ldsRed[par][2][r][c0];
            float4 s3 = *(const float4*)&ldsRed[par][3][r][c0];
            s.x = s0.x + s1.x + s2.x + s3.x;
            s.y = s0.y + s1.y + s2.y + s3.y;
            s.z = s0.z + s1.z + s2.z + s3.z;
            s.w = s0.w + s1.w + s2.w + s3.w;
        }

        float4 hv;
        hv.x = fast_tanh(xw.x + s.x);
        hv.y = fast_tanh(xw.y + s.y);
        hv.z = fast_tanh(xw.z + s.z);
        hv.w = fast_tanh(xw.w + s.w);

        *(float4*)&out[(nF * TT + t) * HH + jE] = hv;

        if (t + 1 < TT) {                      // post h_t (system scope)
            u32 h0b, l0b, h1b, l1b, h2b, l2b, h3b, l3b;
            split2(hv.x, h0b, l0b);
            split2(hv.y, h1b, l1b);
            split2(hv.z, h2b, l2b);
            split2(hv.w, h3b, l3b);
            int dst = (par ^ 1) * NN * HH + nF * HH + jE;      // 8B aligned
            st8_sys((u32*)(hbH + dst), h0b | (h1b << 16), h2b | (h3b << 16));
            st8_sys((u32*)(hbL + dst), l0b | (l1b << 16), l2b | (l3b << 16));
            wait_vm0();                        // posts (+out store) acked
            if (l == 0) st_flag(gflags + cb * 4 + w, (u32)(t + 1));
            // prefetch next xw (completes under next poll)
            xw = *(const float4*)&out[(nF * TT + t + 1) * HH + jE];
        }
    }
}

// ---------------------------------------------------------------------------
extern "C" void kernel_launch(void* const* d_in, const int* in_sizes, int n_in,
                              void* d_out, int out_size, void* d_ws, size_t ws_size,
                              hipStream_t stream) {
    const float* x  = (const float*)d_in[0];
    const float* h0 = (const float*)d_in[1];
    const float* Wx = (const float*)d_in[2];
    const float* Wh = (const float*)d_in[3];
    const float* b  = (const float*)d_in[4];
    float* out = (float*)d_out;

    char* ws = (char*)d_ws;
    u16* WxPh = (u16*)(ws);                           // 1 MB
    u16* WxPl = (u16*)(ws + (1u << 20));              // 1 MB
    u16* WhPh = (u16*)(ws + (2u << 20));              // 2 MB
    u16* WhPl = (u16*)(ws + (4u << 20));              // 2 MB
    u16* hbH  = (u16*)(ws + (6u << 20));              // [2][64][1024] u16 = 256 KB
    u16* hbL  = (u16*)(ws + (6u << 20) + (1u << 18)); // 256 KB
    u32* flags= (u32*)(ws + (6u << 20) + (1u << 19)); // 4 groups x 64 u32 = 1 KB

    hipMemsetAsync(flags, 0, 4 * 64 * sizeof(u32), stream);
    prep_kernel<<<2048, 256, 0, stream>>>(Wx, Wh, h0, WxPh, WxPl, WhPh, WhPl,
                                          hbH, hbL);
    gemm_kernel<<<2048, 256, 0, stream>>>(x, b, WxPh, WxPl, out);
    scan_kernel<<<64, 256, 0, stream>>>(WhPh, WhPl, hbH, hbL, out, flags);
}

// Round 8
// 2078.123 us; speedup vs baseline: 1.2905x; 1.2905x over previous
//
#include <hip/hip_runtime.h>

// RNN: out[n,t,:] = tanh(x[n,t,:]@Wx + b + h_{t-1}@Wh),  h_{-1} = h0
// N=64, T=512, D=512, H=1024, fp32 in/out.
// Round 8: Wh resident in LDS (deterministic). Flag-free h exchange:
// packed u32 (hi|lo) with epoch tag bit in lo-LSB; consumers poll the
// data itself (no producer ack, no flags). 128 blocks = 4 groups x 32
// col-tiles; exec-masked retries cap poll traffic.

#define NN 64
#define TT 512
#define DD 512
#define HH 1024

typedef unsigned int  u32;
typedef unsigned short u16;

typedef __attribute__((ext_vector_type(8))) short bf16x8;
typedef __attribute__((ext_vector_type(4))) float f32x4;
typedef __attribute__((ext_vector_type(4))) u32   u32x4;
typedef __attribute__((ext_vector_type(2))) u32   u32x2;

#define MFMA16(a, b, c) __builtin_amdgcn_mfma_f32_16x16x32_bf16((a), (b), (c), 0, 0, 0)

__device__ __forceinline__ u32 bf16r(float f) {          // RTNE fp32->bf16 (bits)
    u32 u = __float_as_uint(f);
    return (u + 0x7fffu + ((u >> 16) & 1u)) >> 16;
}
__device__ __forceinline__ float bf16tof(u32 h) { return __uint_as_float(h << 16); }
__device__ __forceinline__ void split2(float f, u32& hi, u32& lo) {
    hi = bf16r(f);
    lo = bf16r(f - bf16tof(hi));
}

// ---- system-scope (sc0 sc1) ops; no "memory" clobbers ----------------------
__device__ __forceinline__ u32x4 ld16_sys(const u32* p) {   // issue-only
    u32x4 v;
    asm volatile("global_load_dwordx4 %0, %1, off sc0 sc1" : "=v"(v) : "v"(p));
    return v;
}
__device__ __forceinline__ void st8_sys(u32* p, u32 v0, u32 v1) {
    u32x2 v = {v0, v1};
    asm volatile("global_store_dwordx2 %0, %1, off sc0 sc1" :: "v"(p), "v"(v));
}
__device__ __forceinline__ void wait_vm0() {
    asm volatile("s_waitcnt vmcnt(0)");
}

__device__ __forceinline__ float fast_tanh(float x) {
    float e = __expf(2.0f * x);
    return 1.0f - __fdividef(2.0f, e + 1.0f);   // exact +/-1 saturation
}

// ---------------------------------------------------------------------------
// Prep: pack Wx and Wh into MFMA-fragment order (hi/lo bf16); pack h0 with
// tag bit. h buffer: u32 [2 parity][64][1024], value = hi<<16 | lo&0xFFFE | tag.
// h_s lives in buf[s&1] with tag (s>>1)&1;  h_{-1}=h0 -> buf[1], tag 1.
// buf[0] must start with tag bit 1 (stale marker for the t=1 readers).
// ---------------------------------------------------------------------------
__global__ __launch_bounds__(256) void prep_kernel(
    const float* __restrict__ Wx, const float* __restrict__ Wh,
    const float* __restrict__ h0,
    u16* __restrict__ WxPh, u16* __restrict__ WxPl,
    u16* __restrict__ WhPh, u16* __restrict__ WhPl,
    u32* __restrict__ hpk)
{
    const int stride = gridDim.x * 256;
    const int gid = blockIdx.x * 256 + threadIdx.x;

    for (int p = gid; p < 64 * 16 * 64 * 8; p += stride) {   // Wx
        int e = p & 7, l = (p >> 3) & 63, kb = (p >> 9) & 15, jt = p >> 13;
        int j = jt * 16 + (l & 15);
        int k = kb * 32 + ((l >> 4) << 3) + e;
        u32 hi, lo; split2(Wx[k * HH + j], hi, lo);
        WxPh[p] = (u16)hi; WxPl[p] = (u16)lo;
    }
    for (int p = gid; p < 64 * 32 * 64 * 8; p += stride) {   // Wh
        int e = p & 7, l = (p >> 3) & 63, kb = (p >> 9) & 31, jt = p >> 14;
        int j = jt * 16 + (l & 15);
        int k = kb * 32 + ((l >> 4) << 3) + e;
        u32 hi, lo; split2(Wh[k * HH + j], hi, lo);
        WhPh[p] = (u16)hi; WhPl[p] = (u16)lo;
    }
    for (int p = gid; p < NN * HH; p += stride) {            // h0
        u32 hi, lo; split2(h0[p], hi, lo);
        hpk[NN * HH + p] = (hi << 16) | (lo & 0xFFFEu) | 1u; // buf[1], tag 1
        hpk[p] = 1u;                                         // buf[0] stale tag
    }
}

// ---------------------------------------------------------------------------
// Phase 1: out = x@Wx + b   (split-bf16, 128x128 tiles, grid 2048)
// ---------------------------------------------------------------------------
__global__ __launch_bounds__(256) void gemm_kernel(
    const float* __restrict__ x, const float* __restrict__ b,
    const u16* __restrict__ WxPh, const u16* __restrict__ WxPl,
    float* __restrict__ out)
{
    __shared__ __align__(16) u32 ldsA[2][128][20];

    const int tid = threadIdx.x;
    const int bid = blockIdx.x;
    const int w   = tid >> 6;
    const int l   = tid & 63;
    const int wm = w >> 1, wj = w & 1;

    const int m0 = (bid >> 3) * 128;
    const int jb = bid & 7;
    const int j0 = jb * 128;

    f32x4 acc[4][4] = {};
    for (int ks = 0; ks < 16; ++ks) {
        const int k0 = ks * 32;
        #pragma unroll
        for (int it = 0; it < 8; ++it) {
            int idx = it * 256 + tid;
            int m = idx >> 4, kp = idx & 15;
            float2 v = *(const float2*)(x + (m0 + m) * DD + k0 + kp * 2);
            u32 h0b, l0b, h1b, l1b;
            split2(v.x, h0b, l0b);
            split2(v.y, h1b, l1b);
            ldsA[0][m][kp] = h0b | (h1b << 16);
            ldsA[1][m][kp] = l0b | (l1b << 16);
        }
        __syncthreads();

        bf16x8 afh[4], afl[4], bfh[4], bfl[4];
        #pragma unroll
        for (int mt4 = 0; mt4 < 4; ++mt4) {
            int row = wm * 64 + mt4 * 16 + (l & 15);
            int co  = (l >> 4) * 4;
            afh[mt4] = *(const bf16x8*)&ldsA[0][row][co];
            afl[mt4] = *(const bf16x8*)&ldsA[1][row][co];
        }
        #pragma unroll
        for (int jt4 = 0; jt4 < 4; ++jt4) {
            int jtile = jb * 8 + wj * 4 + jt4;
            int off = ((jtile * 16 + ks) * 64 + l) * 8;
            bfh[jt4] = *(const bf16x8*)(WxPh + off);
            bfl[jt4] = *(const bf16x8*)(WxPl + off);
        }
        #pragma unroll
        for (int mt4 = 0; mt4 < 4; ++mt4)
            #pragma unroll
            for (int jt4 = 0; jt4 < 4; ++jt4) {
                acc[mt4][jt4] = MFMA16(afh[mt4], bfh[jt4], acc[mt4][jt4]);
                acc[mt4][jt4] = MFMA16(afh[mt4], bfl[jt4], acc[mt4][jt4]);
                acc[mt4][jt4] = MFMA16(afl[mt4], bfh[jt4], acc[mt4][jt4]);
            }
        __syncthreads();
    }
    #pragma unroll
    for (int jt4 = 0; jt4 < 4; ++jt4) {
        int j = j0 + wj * 64 + jt4 * 16 + (l & 15);
        float bj = b[j];
        #pragma unroll
        for (int mt4 = 0; mt4 < 4; ++mt4)
            #pragma unroll
            for (int r = 0; r < 4; ++r) {
                int m = m0 + wm * 64 + mt4 * 16 + (l >> 4) * 4 + r;
                out[m * HH + j] = acc[mt4][jt4][r] + bj;
            }
    }
}

// ---------------------------------------------------------------------------
// Phase 2: scan. Grid 128 x 256. Group g = bid&3 owns rows [16g,16g+16);
// block cb = bid>>2 owns cols [32cb,32cb+32); wave w owns k [256w,+256).
// Wh slice (32 cols x 1024 K x hi/lo) lives in LDS, fragment-ordered.
// h exchange: packed u32 with tag bit; consumers poll data directly.
// ---------------------------------------------------------------------------
__global__ __launch_bounds__(256, 1) void scan_kernel(
    const u16* __restrict__ WhPh, const u16* __restrict__ WhPl,
    u32* __restrict__ hbuf,          // [2][64][1024] packed
    float* __restrict__ out)
{
    __shared__ __align__(16) char ldsWhH[65536];   // 64 frags x 1KB
    __shared__ __align__(16) char ldsWhL[65536];
    __shared__ float ldsRed[2][4][16][34];

    const int tid = threadIdx.x;
    const int bid = blockIdx.x;
    const int g   = bid & 3;
    const int cb  = bid >> 2;
    const int w   = tid >> 6;
    const int l   = tid & 63;

    // ---- stage Wh fragments into LDS (once) ----
    // frag f = (w*2+jj)*8+i  <->  global frag (cb*2+jj)*32 + (w*8+i)
    for (int c = tid; c < 4096; c += 256) {        // 4096 x 16B chunks
        int f = c >> 6, p = c & 63;
        int fw = f >> 4, fj = (f >> 3) & 1, fi = f & 7;
        int src = (((cb * 2 + fj) * 32) + (fw * 8 + fi)) * 512 + p * 8;
        *(u32x4*)(ldsWhH + c * 16) = *(const u32x4*)(WhPh + src);
        *(u32x4*)(ldsWhL + c * 16) = *(const u32x4*)(WhPl + src);
    }
    __syncthreads();

    const int nA    = g * 16 + (l & 15);           // A-frag batch row
    const int kbase = w * 256 + ((l >> 4) << 3);

    const int rF = tid >> 4;                       // row this thread finalizes
    const int nF = g * 16 + rF;
    const int c0 = (tid & 15) * 2;                 // col pair within 32
    const int jE = cb * 32 + c0;

    float2 xw = *(const float2*)&out[(nF * TT) * HH + jE];

    for (int t = 0; t < TT; ++t) {
        // ---- issue Wh ds_reads (complete under the poll spin) ----
        u32x4 bh[2][8], bl[2][8];
        #pragma unroll
        for (int jj = 0; jj < 2; ++jj)
            #pragma unroll
            for (int i = 0; i < 8; ++i) {
                int off = (((w * 2 + jj) * 8 + i) << 10) + (l << 4);
                bh[jj][i] = *(const u32x4*)(ldsWhH + off);
                bl[jj][i] = *(const u32x4*)(ldsWhL + off);
            }
        __builtin_amdgcn_sched_barrier(0);

        // ---- poll h_{t-1} directly (tag-validated data) ----
        const u32 tg = (u32)(((t - 1) >> 1) & 1);  // arithmetic shift: t=0 -> 1
        const u32* hp = hbuf + ((t - 1) & 1) * NN * HH + nA * HH + kbase;

        u32x4 a0[8], a1[8];
        bool ready = false;
        do {
            if (!ready) {
                #pragma unroll
                for (int i = 0; i < 8; ++i) {
                    a0[i] = ld16_sys(hp + i * 32);
                    a1[i] = ld16_sys(hp + i * 32 + 4);
                }
                wait_vm0();
                if (tg) {
                    u32 c = ~0u;
                    #pragma unroll
                    for (int i = 0; i < 8; ++i) {
                        c &= a0[i][0] & a0[i][1] & a0[i][2] & a0[i][3];
                        c &= a1[i][0] & a1[i][1] & a1[i][2] & a1[i][3];
                    }
                    ready = (c & 1u) != 0u;
                } else {
                    u32 c = 0u;
                    #pragma unroll
                    for (int i = 0; i < 8; ++i) {
                        c |= a0[i][0] | a0[i][1] | a0[i][2] | a0[i][3];
                        c |= a1[i][0] | a1[i][1] | a1[i][2] | a1[i][3];
                    }
                    ready = (c & 1u) == 0u;
                }
            }
        } while (__ballot(!ready) != 0ull);
        __builtin_amdgcn_sched_barrier(0);

        // ---- unpack h + MFMA ----
        f32x4 ahh[2] = {}, ahl[2] = {}, alh[2] = {};
        #pragma unroll
        for (int i = 0; i < 8; ++i) {
            bf16x8 Ah, Al;
            #pragma unroll
            for (int e = 0; e < 4; ++e) {
                u32 u0 = a0[i][e], u1 = a1[i][e];
                Ah[e]     = (short)(u0 >> 16);
                Al[e]     = (short)(u0 & 0xFFFEu);
                Ah[4 + e] = (short)(u1 >> 16);
                Al[4 + e] = (short)(u1 & 0xFFFEu);
            }
            #pragma unroll
            for (int jj = 0; jj < 2; ++jj) {
                bf16x8 Bh = __builtin_bit_cast(bf16x8, bh[jj][i]);
                bf16x8 Bl = __builtin_bit_cast(bf16x8, bl[jj][i]);
                ahh[jj] = MFMA16(Ah, Bh, ahh[jj]);
                ahl[jj] = MFMA16(Ah, Bl, ahl[jj]);
                alh[jj] = MFMA16(Al, Bh, alh[jj]);
            }
        }

        // ---- cross-wave reduce (double-buffered, one barrier/step) ----
        const int par = t & 1;
        {
            int rb = (l >> 4) * 4, cc = l & 15;
            #pragma unroll
            for (int jj = 0; jj < 2; ++jj) {
                f32x4 s4 = ahh[jj] + ahl[jj] + alh[jj];
                #pragma unroll
                for (int e = 0; e < 4; ++e)
                    ldsRed[par][w][rb + e][jj * 16 + cc] = s4[e];
            }
        }
        __syncthreads();

        float sx = 0.f, sy = 0.f;
        #pragma unroll
        for (int wq = 0; wq < 4; ++wq) {
            float2 v = *(const float2*)&ldsRed[par][wq][rF][c0];
            sx += v.x; sy += v.y;
        }
        float hv0 = fast_tanh(xw.x + sx);
        float hv1 = fast_tanh(xw.y + sy);

        *(float2*)&out[(nF * TT + t) * HH + jE] = make_float2(hv0, hv1);

        if (t + 1 < TT) {                          // fire-and-forget tagged post
            const u32 tagw = (u32)((t >> 1) & 1);
            u32 h0b, l0b, h1b, l1b;
            split2(hv0, h0b, l0b);
            split2(hv1, h1b, l1b);
            u32 p0 = (h0b << 16) | (l0b & 0xFFFEu) | tagw;
            u32 p1 = (h1b << 16) | (l1b & 0xFFFEu) | tagw;
            st8_sys(hbuf + par * NN * HH + nF * HH + jE, p0, p1);
            xw = *(const float2*)&out[(nF * TT + t + 1) * HH + jE];
        }
    }
}

// ---------------------------------------------------------------------------
extern "C" void kernel_launch(void* const* d_in, const int* in_sizes, int n_in,
                              void* d_out, int out_size, void* d_ws, size_t ws_size,
                              hipStream_t stream) {
    const float* x  = (const float*)d_in[0];
    const float* h0 = (const float*)d_in[1];
    const float* Wx = (const float*)d_in[2];
    const float* Wh = (const float*)d_in[3];
    const float* b  = (const float*)d_in[4];
    float* out = (float*)d_out;

    char* ws = (char*)d_ws;
    u16* WxPh = (u16*)(ws);                           // 1 MB
    u16* WxPl = (u16*)(ws + (1u << 20));              // 1 MB
    u16* WhPh = (u16*)(ws + (2u << 20));              // 2 MB
    u16* WhPl = (u16*)(ws + (4u << 20));              // 2 MB
    u32* hbuf = (u32*)(ws + (6u << 20));              // [2][64][1024] u32 = 512 KB

    prep_kernel<<<2048, 256, 0, stream>>>(Wx, Wh, h0, WxPh, WxPl, WhPh, WhPl, hbuf);
    gemm_kernel<<<2048, 256, 0, stream>>>(x, b, WxPh, WxPl, out);
    scan_kernel<<<128, 256, 0, stream>>>(WhPh, WhPl, hbuf, out);
}